// Round 7
// baseline (342.312 us; speedup 1.0000x reference)
//
#include <hip/hip_runtime.h>
#include <hip/hip_cooperative_groups.h>
#include <math.h>

namespace cg = cooperative_groups;

#define BB 4
#define NQ 256
#define NK 1024
#define DD 256
#define HH 256
#define NBLK 512

#define TM 64
#define TN 64
#define TKK 16
#define NT (DD / TKK)   // 16 k-steps

// Shared-memory union across phases. Max member = scores (67.6 KB) -> 2 blocks/CU.
struct SMem {
    union {
        struct { float As[2][TKK][TM + 4]; float Ws[2][TKK][TN + 4]; } p;     // 17.4 KB
        struct { float sQ[32][HH + 4]; float sK[32][HH + 4]; float sW[HH]; } s; // 67.6 KB
        struct { float sPt[2][32][36]; float sV[2][32][36]; float sAll[3][64][17]; } v; // 31.5 KB
    } u;
};

// ---------------- Phase 1: projection tile + E=exp(2x) epilogue -------------
// E[m,h] = exp(2*clamp(sum_d A[m,d]*W[d,h], -8, 8)); tanh identity applied
// implicitly downstream (tanh(z) = 1 - 2/(1+e^{2z}); sum_h w_h cancels in
// softmax). Double-buffered, one barrier per k-step.
__device__ __forceinline__ void proj_tile(
    SMem& sm, int tid, const float* __restrict__ A, const float* __restrict__ W,
    float* __restrict__ C, int bm, int bn)
{
    auto& As = sm.u.p.As;
    auto& Ws = sm.u.p.Ws;
    int ar = tid >> 2, ac4 = tid & 3;
    int wkk = tid >> 4, wc4 = tid & 15;
    int ty = tid >> 4, tx = tid & 15;

    float4 aR = *(const float4*)&A[(size_t)(bm + ar) * DD + ac4 * 4];
    float4 wR = *(const float4*)&W[(size_t)wkk * HH + bn + wc4 * 4];

    float acc[4][4] = {};

    for (int t = 0; t < NT; ++t) {
        int cur = t & 1;
        As[cur][ac4 * 4 + 0][ar] = aR.x;
        As[cur][ac4 * 4 + 1][ar] = aR.y;
        As[cur][ac4 * 4 + 2][ar] = aR.z;
        As[cur][ac4 * 4 + 3][ar] = aR.w;
        *(float4*)&Ws[cur][wkk][wc4 * 4] = wR;
        if (t + 1 < NT) {
            int k0 = (t + 1) * TKK;
            aR = *(const float4*)&A[(size_t)(bm + ar) * DD + k0 + ac4 * 4];
            wR = *(const float4*)&W[(size_t)(k0 + wkk) * HH + bn + wc4 * 4];
        }
        __syncthreads();
#pragma unroll
        for (int kk = 0; kk < TKK; ++kk) {
            float4 a4 = *(const float4*)&As[cur][kk][ty * 4];
            float4 w4 = *(const float4*)&Ws[cur][kk][tx * 4];
            acc[0][0] = fmaf(a4.x, w4.x, acc[0][0]);
            acc[0][1] = fmaf(a4.x, w4.y, acc[0][1]);
            acc[0][2] = fmaf(a4.x, w4.z, acc[0][2]);
            acc[0][3] = fmaf(a4.x, w4.w, acc[0][3]);
            acc[1][0] = fmaf(a4.y, w4.x, acc[1][0]);
            acc[1][1] = fmaf(a4.y, w4.y, acc[1][1]);
            acc[1][2] = fmaf(a4.y, w4.z, acc[1][2]);
            acc[1][3] = fmaf(a4.y, w4.w, acc[1][3]);
            acc[2][0] = fmaf(a4.z, w4.x, acc[2][0]);
            acc[2][1] = fmaf(a4.z, w4.y, acc[2][1]);
            acc[2][2] = fmaf(a4.z, w4.z, acc[2][2]);
            acc[2][3] = fmaf(a4.z, w4.w, acc[2][3]);
            acc[3][0] = fmaf(a4.w, w4.x, acc[3][0]);
            acc[3][1] = fmaf(a4.w, w4.y, acc[3][1]);
            acc[3][2] = fmaf(a4.w, w4.z, acc[3][2]);
            acc[3][3] = fmaf(a4.w, w4.w, acc[3][3]);
        }
        // dbuf: next iter writes the other buffer; no trailing barrier needed
    }

#pragma unroll
    for (int i = 0; i < 4; ++i) {
        int m = bm + ty * 4 + i;
        float4 o;
        o.x = __expf(2.f * fminf(fmaxf(acc[i][0], -8.f), 8.f));
        o.y = __expf(2.f * fminf(fmaxf(acc[i][1], -8.f), 8.f));
        o.z = __expf(2.f * fminf(fmaxf(acc[i][2], -8.f), 8.f));
        o.w = __expf(2.f * fminf(fmaxf(acc[i][3], -8.f), 8.f));
        *(float4*)&C[(size_t)m * HH + bn + tx * 4] = o;
    }
}

// ---------------- Phase 2: scores tile -> P = exp(-2T) + chunk row sums -----
// T(q,k) = sum_h w_h/(1+Eq_h*Ek_h). Quad-batched rational: 1 v_rcp / 4 terms.
__device__ __forceinline__ void scores_tile(
    SMem& sm, int tid, const float* __restrict__ Eq, const float* __restrict__ Ek,
    const float* __restrict__ wv, int b, int q0, int k0, int kc, int L,
    float* __restrict__ P, float* __restrict__ Psum)
{
    auto& sQ = sm.u.s.sQ;
    auto& sK = sm.u.s.sK;
    auto& sW = sm.u.s.sW;

    {
        int c4 = tid & 63, r0 = tid >> 6;
        const float4* gq = (const float4*)(Eq + ((size_t)b * NQ + q0) * HH);
        const float4* gk = (const float4*)(Ek + ((size_t)b * NK + k0) * HH);
#pragma unroll
        for (int r = 0; r < 32; r += 4) {
            *(float4*)&sQ[r + r0][c4 * 4] = gq[(size_t)(r + r0) * (HH / 4) + c4];
            *(float4*)&sK[r + r0][c4 * 4] = gk[(size_t)(r + r0) * (HH / 4) + c4];
        }
        sW[tid] = wv[tid];
    }
    __syncthreads();

    int ki = tid & 15, qi = tid >> 4;
    float a00 = 0.f, a01 = 0.f, a10 = 0.f, a11 = 0.f;
    const float4* qp0 = (const float4*)&sQ[qi][0];
    const float4* qp1 = (const float4*)&sQ[qi + 16][0];
    const float4* kp0 = (const float4*)&sK[ki][0];
    const float4* kp1 = (const float4*)&sK[ki + 16][0];
    const float4* wp  = (const float4*)sW;

#pragma unroll 4
    for (int h4 = 0; h4 < HH / 4; ++h4) {
        float4 w = wp[h4];
        float wxy = w.x + w.y, wzw = w.z + w.w;
        float4 A0 = qp0[h4], A1 = qp1[h4];
        float4 B0 = kp0[h4], B1 = kp1[h4];
#define QUAD(acc, Aq, Bk)                                                    \
        {                                                                    \
            float E1 = Aq.x * Bk.x, E2 = Aq.y * Bk.y;                        \
            float E3 = Aq.z * Bk.z, E4 = Aq.w * Bk.w;                        \
            float d1 = E1 + 1.f, d2 = E2 + 1.f;                              \
            float d3 = E3 + 1.f, d4 = E4 + 1.f;                              \
            float n12 = fmaf(w.x, E2, fmaf(w.y, E1, wxy));                   \
            float n34 = fmaf(w.z, E4, fmaf(w.w, E3, wzw));                   \
            float d12 = d1 * d2, d34 = d3 * d4;                              \
            float num = fmaf(n12, d34, n34 * d12);                           \
            acc = fmaf(num, __builtin_amdgcn_rcpf(d12 * d34), acc);          \
        }
        QUAD(a00, A0, B0);
        QUAD(a01, A0, B1);
        QUAD(a10, A1, B0);
        QUAD(a11, A1, B1);
#undef QUAD
    }

    int kA = k0 + ki, kB = kA + 16;
    float p00 = (kA < L) ? __expf(-2.f * a00) : 0.f;
    float p10 = (kA < L) ? __expf(-2.f * a10) : 0.f;
    float p01 = (kB < L) ? __expf(-2.f * a01) : 0.f;
    float p11 = (kB < L) ? __expf(-2.f * a11) : 0.f;

    float* s0 = P + ((size_t)b * NQ + q0 + qi) * NK;
    float* s1 = P + ((size_t)b * NQ + q0 + qi + 16) * NK;
    s0[kA] = p00; s0[kB] = p01;
    s1[kA] = p10; s1[kB] = p11;

    float r0s = p00 + p01, r1s = p10 + p11;
#pragma unroll
    for (int o = 1; o <= 8; o <<= 1) {
        r0s += __shfl_xor(r0s, o, 64);
        r1s += __shfl_xor(r1s, o, 64);
    }
    if (ki == 0) {
        Psum[((size_t)b * NQ + q0 + qi) * 32 + kc] = r0s;
        Psum[((size_t)b * NQ + q0 + qi + 16) * 32 + kc] = r1s;
    }
}

// ---------------- Fused cooperative kernel ----------------------------------
__global__ __launch_bounds__(256, 2) void fused_kernel(
    const float* __restrict__ queries, const float* __restrict__ keys,
    const float* __restrict__ values, const int* __restrict__ vlen,
    const float* __restrict__ Wq, const float* __restrict__ Wk,
    const float* __restrict__ wv, float* __restrict__ out,
    float* __restrict__ Eqb, float* __restrict__ Ekb,
    float* __restrict__ P, float* __restrict__ Psum,
    float* __restrict__ Opart, float* __restrict__ Rsum,
    int pl, int ph)
{
    __shared__ SMem sm;
    cg::grid_group grid = cg::this_grid();
    int tid = threadIdx.x;

    // ---- Phase 1: projections (320 tiles; fully-masked K-tiles skipped) ----
    if (pl <= 1 && ph >= 1) {
        int t = blockIdx.x;
        if (t < 320) {
            int rt = t >> 2, ct = t & 3;
            bool active = true;
            const float* A; const float* W; float* C; int bm;
            if (rt < 16) { A = queries; W = Wq; C = Eqb; bm = rt * TM; }
            else {
                int kt = rt - 16;
                int b = kt >> 4, lr = (kt & 15) * TM;
                if (lr >= vlen[b]) active = false;
                A = keys; W = Wk; C = Ekb; bm = kt * TM;
            }
            if (active) proj_tile(sm, tid, A, W, C, bm, ct * TN);
        }
    }
    if (pl <= 1 && ph >= 2) { __threadfence(); grid.sync(); }

    // ---- Phase 2: scores (1024 tile slots, 2 per block) ----
    if (pl <= 2 && ph >= 2) {
        bool first = true;
        for (int t = blockIdx.x; t < 1024; t += NBLK) {
            int b = t & 3, qc = (t >> 2) & 7, kc = t >> 5;
            int L = vlen[b];
            int k0 = kc * 32;
            if (k0 >= L) continue;           // block-uniform skip
            if (!first) __syncthreads();     // protect LDS reuse across tiles
            first = false;
            scores_tile(sm, tid, Eqb, Ekb, wv, b, qc * 32, k0, kc, L, P, Psum);
        }
    }
    if (pl <= 2 && ph >= 3) { __threadfence(); grid.sync(); }

    // ---- Phase 3: PV partial GEMM (512 tiles = 2-way k-split) + row sums ----
    if (pl <= 3 && ph >= 3) {
        int t = blockIdx.x;
        int b = t & 3, qt = (t >> 2) & 7, dt = (t >> 5) & 7, seg = t >> 8;
        int q0 = qt * 32, d0 = dt * 32;
        int L = vlen[b];
        int nc = (L + 31) >> 5;
        int nch = (nc + 1) >> 1;
        int c0 = seg ? nch : 0;
        int c1 = seg ? nc : nch;

        if (seg == 0 && dt == 0 && tid < 32) {   // row sums -> Rsum
            float ssum = 0.f;
            const float* pp = Psum + ((size_t)b * NQ + q0 + tid) * 32;
            for (int c = 0; c < nc; ++c) ssum += pp[c];
            Rsum[b * NQ + q0 + tid] = ssum;
        }

        auto& sPt = sm.u.v.sPt;
        auto& sV  = sm.u.v.sV;
        auto& sAll = sm.u.v.sAll;

        int r = tid >> 3, c4 = tid & 7;
        int w = tid >> 6, sp = tid & 63;
        int qg = sp >> 3, dg = sp & 7;

        const float* Pb = P + ((size_t)b * NQ + q0 + r) * NK;
        const float* Vb = values + (size_t)b * NK * DD + d0;

        int cld = (c0 < c1) ? c0 : 0;            // address-safe prefetch
        float4 pf = *(const float4*)(Pb + cld * 32 + c4 * 4);
        float4 vf = *(const float4*)(Vb + (size_t)(cld * 32 + r) * DD + c4 * 4);

        float acc[4][4] = {};

        for (int c = c0; c < c1; ++c) {
            int cur = c & 1;
            sPt[cur][c4 * 4 + 0][r] = pf.x;
            sPt[cur][c4 * 4 + 1][r] = pf.y;
            sPt[cur][c4 * 4 + 2][r] = pf.z;
            sPt[cur][c4 * 4 + 3][r] = pf.w;
            *(float4*)&sV[cur][r][c4 * 4] = vf;
            if (c + 1 < c1) {
                int kn = (c + 1) * 32;
                pf = *(const float4*)(Pb + kn + c4 * 4);
                vf = *(const float4*)(Vb + (size_t)(kn + r) * DD + c4 * 4);
            }
            __syncthreads();
#pragma unroll
            for (int kk = 0; kk < 8; ++kk) {
                float4 A  = *(const float4*)&sPt[cur][w * 8 + kk][qg * 4];
                float4 Bv = *(const float4*)&sV[cur][w * 8 + kk][dg * 4];
                acc[0][0] = fmaf(A.x, Bv.x, acc[0][0]);
                acc[0][1] = fmaf(A.x, Bv.y, acc[0][1]);
                acc[0][2] = fmaf(A.x, Bv.z, acc[0][2]);
                acc[0][3] = fmaf(A.x, Bv.w, acc[0][3]);
                acc[1][0] = fmaf(A.y, Bv.x, acc[1][0]);
                acc[1][1] = fmaf(A.y, Bv.y, acc[1][1]);
                acc[1][2] = fmaf(A.y, Bv.z, acc[1][2]);
                acc[1][3] = fmaf(A.y, Bv.w, acc[1][3]);
                acc[2][0] = fmaf(A.z, Bv.x, acc[2][0]);
                acc[2][1] = fmaf(A.z, Bv.y, acc[2][1]);
                acc[2][2] = fmaf(A.z, Bv.z, acc[2][2]);
                acc[2][3] = fmaf(A.z, Bv.w, acc[2][3]);
                acc[3][0] = fmaf(A.w, Bv.x, acc[3][0]);
                acc[3][1] = fmaf(A.w, Bv.y, acc[3][1]);
                acc[3][2] = fmaf(A.w, Bv.z, acc[3][2]);
                acc[3][3] = fmaf(A.w, Bv.w, acc[3][3]);
            }
        }

        if (w > 0) {
#pragma unroll
            for (int i = 0; i < 4; ++i)
#pragma unroll
                for (int j = 0; j < 4; ++j) sAll[w - 1][sp][i * 4 + j] = acc[i][j];
        }
        __syncthreads();
        if (w == 0) {
#pragma unroll
            for (int ww = 0; ww < 3; ++ww)
#pragma unroll
                for (int i = 0; i < 4; ++i)
#pragma unroll
                    for (int j = 0; j < 4; ++j) acc[i][j] += sAll[ww][sp][i * 4 + j];
            float* op = Opart + (size_t)seg * (BB * NQ * DD);
#pragma unroll
            for (int i = 0; i < 4; ++i) {
                float4 o = { acc[i][0], acc[i][1], acc[i][2], acc[i][3] };
                *(float4*)&op[((size_t)b * NQ + q0 + qg * 4 + i) * DD + d0 + dg * 4] = o;
            }
        }
    }
    if (pl <= 3 && ph >= 4) { __threadfence(); grid.sync(); }

    // ---- Phase 4: combine partials, normalize ----
    if (pl <= 4 && ph >= 4) {
        int idx = blockIdx.x * 256 + tid;
        if (idx < BB * NQ * DD / 4) {
            int row = idx >> 6, d4 = idx & 63;
            const size_t SEG = (size_t)BB * NQ * DD;
            float4 o0 = *(const float4*)&Opart[(size_t)row * DD + d4 * 4];
            float4 o1 = *(const float4*)&Opart[SEG + (size_t)row * DD + d4 * 4];
            float rinv = 1.0f / Rsum[row];
            float4 o = { (o0.x + o1.x) * rinv, (o0.y + o1.y) * rinv,
                         (o0.z + o1.z) * rinv, (o0.w + o1.w) * rinv };
            *(float4*)&out[(size_t)row * DD + d4 * 4] = o;
        }
    }
}

extern "C" void kernel_launch(void* const* d_in, const int* in_sizes, int n_in,
                              void* d_out, int out_size, void* d_ws, size_t ws_size,
                              hipStream_t stream) {
    const float* queries = (const float*)d_in[0];  // [B,NQ,D]
    const float* keys    = (const float*)d_in[1];  // [B,NK,D]
    const float* values  = (const float*)d_in[2];  // [B,NK,D]
    const int*   vlens   = (const int*)d_in[3];    // [B]
    const float* Wq      = (const float*)d_in[4];  // [D,H]
    const float* Wk      = (const float*)d_in[5];  // [D,H]
    const float* wv      = (const float*)d_in[6];  // [H]
    float* out = (float*)d_out;

    float* Eqb   = (float*)d_ws;                           // 1 MB
    float* Ekb   = Eqb + (size_t)BB * NQ * HH;             // 4 MB
    float* P     = Ekb + (size_t)BB * NK * HH;             // 4 MB
    float* Psum  = P + (size_t)BB * NQ * NK;               // 128 KB
    float* Opart = Psum + (size_t)BB * NQ * 32;            // 2 MB
    float* Rsum  = Opart + (size_t)2 * BB * NQ * DD;       // 4 KB

    int pl = 1, ph = 4;
    void* args[] = { (void*)&queries, (void*)&keys, (void*)&values, (void*)&vlens,
                     (void*)&Wq, (void*)&Wk, (void*)&wv, (void*)&out,
                     (void*)&Eqb, (void*)&Ekb, (void*)&P, (void*)&Psum,
                     (void*)&Opart, (void*)&Rsum, (void*)&pl, (void*)&ph };
    hipError_t e = hipLaunchCooperativeKernel((void*)fused_kernel,
                                              dim3(NBLK), dim3(256),
                                              args, 0, stream);
    if (e != hipSuccess) {
        // Fallback: same kernel, phase-by-phase (no grid.sync executed).
        for (int p = 1; p <= 4; ++p)
            fused_kernel<<<dim3(NBLK), dim3(256), 0, stream>>>(
                queries, keys, values, vlens, Wq, Wk, wv, out,
                Eqb, Ekb, P, Psum, Opart, Rsum, p, p);
    }
}

// Round 8
// 59.073 us; speedup vs baseline: 5.7947x; 5.7947x over previous
//
#include <hip/hip_runtime.h>
#include <math.h>

#define BB 4
#define NQ 256
#define NK 1024
#define DD 256
#define HH 256

// ---------------- K1: Projection GEMM (fp32) + E=exp(2x) epilogue ----------
// E[m,h] = exp(2*clamp(sum_d A[m,d]*W[d,h], -8, 8)); tanh(z)=1-2/(1+e^{2z})
// applied implicitly downstream (sum_h w_h cancels in softmax).
// 32x64 tiles -> 640 blocks (~2.5/CU) for latency hiding. Fully-masked
// K-tiles exit early. Double-buffered, one barrier per k-step.
#define TMR 32
#define TNC 64
#define TKK 16
#define NT (DD / TKK)   // 16 k-steps

__global__ __launch_bounds__(256) void proj_exp_kernel(
    const float* __restrict__ Q, const float* __restrict__ K,
    const float* __restrict__ Wq, const float* __restrict__ Wk,
    const int* __restrict__ vlen,
    float* __restrict__ Eq, float* __restrict__ Ek)
{
    const int QROWT = (BB * NQ) / TMR;   // 32 q row-tiles
    int bx = blockIdx.x;
    int rt = bx >> 2, ct = bx & 3;
    const float* A; const float* W; float* C; int bm;
    if (rt < QROWT) { A = Q; W = Wq; C = Eq; bm = rt * TMR; }
    else {
        int kt = rt - QROWT;             // 0..127
        int b = kt >> 5;
        int lr = (kt & 31) * TMR;        // batch-local row start
        if (lr >= vlen[b]) return;       // fully masked K-tile: skip
        A = K; W = Wk; C = Ek; bm = kt * TMR;
    }
    int bn = ct * TNC;

    __shared__ float As[2][TKK][TMR + 2];   // [k][m]
    __shared__ float Ws[2][TKK][TNC + 4];   // [k][n]

    int tid = threadIdx.x;
    int ar = (tid >> 2) & 31, ac4 = tid & 3;   // A stager (tid<128)
    int wkk = tid >> 4, wc4 = tid & 15;        // W stager (all)
    int ty = tid >> 4, tx = tid & 15;          // compute: 2 rows, 4 cols

    float4 aR = {0,0,0,0}, wR;
    if (tid < 128) aR = *(const float4*)&A[(size_t)(bm + ar) * DD + ac4 * 4];
    wR = *(const float4*)&W[(size_t)wkk * HH + bn + wc4 * 4];

    float acc[2][4] = {};

    for (int t = 0; t < NT; ++t) {
        int cur = t & 1;
        if (tid < 128) {
            As[cur][ac4 * 4 + 0][ar] = aR.x;
            As[cur][ac4 * 4 + 1][ar] = aR.y;
            As[cur][ac4 * 4 + 2][ar] = aR.z;
            As[cur][ac4 * 4 + 3][ar] = aR.w;
        }
        *(float4*)&Ws[cur][wkk][wc4 * 4] = wR;
        if (t + 1 < NT) {
            int k0 = (t + 1) * TKK;
            if (tid < 128)
                aR = *(const float4*)&A[(size_t)(bm + ar) * DD + k0 + ac4 * 4];
            wR = *(const float4*)&W[(size_t)(k0 + wkk) * HH + bn + wc4 * 4];
        }
        __syncthreads();
#pragma unroll
        for (int kk = 0; kk < TKK; ++kk) {
            float2 a2 = *(const float2*)&As[cur][kk][ty * 2];
            float4 w4 = *(const float4*)&Ws[cur][kk][tx * 4];
            acc[0][0] = fmaf(a2.x, w4.x, acc[0][0]);
            acc[0][1] = fmaf(a2.x, w4.y, acc[0][1]);
            acc[0][2] = fmaf(a2.x, w4.z, acc[0][2]);
            acc[0][3] = fmaf(a2.x, w4.w, acc[0][3]);
            acc[1][0] = fmaf(a2.y, w4.x, acc[1][0]);
            acc[1][1] = fmaf(a2.y, w4.y, acc[1][1]);
            acc[1][2] = fmaf(a2.y, w4.z, acc[1][2]);
            acc[1][3] = fmaf(a2.y, w4.w, acc[1][3]);
        }
        // dbuf: next iter writes the other buffer; barrier above suffices
    }

#pragma unroll
    for (int i = 0; i < 2; ++i) {
        int m = bm + ty * 2 + i;
        float4 o;
        // clamp +-8: |tanh| error < 2.4e-7, keeps E and quad-products finite
        o.x = __expf(2.f * fminf(fmaxf(acc[i][0], -8.f), 8.f));
        o.y = __expf(2.f * fminf(fmaxf(acc[i][1], -8.f), 8.f));
        o.z = __expf(2.f * fminf(fmaxf(acc[i][2], -8.f), 8.f));
        o.w = __expf(2.f * fminf(fmaxf(acc[i][3], -8.f), 8.f));
        *(float4*)&C[(size_t)m * HH + bn + tx * 4] = o;
    }
}

// ---------------- K2: scores -> P = exp(-2T) + per-chunk row sums -----------
// T(q,k) = sum_h w_h/(1+Eq_h*Ek_h); logit = -2T. One pass over full H per
// 32x32 tile. Quad-batched rational: one v_rcp per 4 h-terms. Masked k ->
// P = 0. Deterministic Psum via shfl. (Byte-identical to the 56.1us config.)
__global__ __launch_bounds__(256) void scores_kernel(
    const float* __restrict__ Eq, const float* __restrict__ Ek,
    const float* __restrict__ wv, const int* __restrict__ vlen,
    float* __restrict__ P, float* __restrict__ Psum)
{
    __shared__ __align__(16) float sQ[32][HH + 4];
    __shared__ __align__(16) float sK[32][HH + 4];
    __shared__ __align__(16) float sW[HH];

    int bid = blockIdx.x;
    int b = bid & 3;                 // batch-interleaved for balance
    int rest = bid >> 2;
    int qc = rest & 7;               // 8 q-chunks of 32
    int kc = rest >> 3;              // 32 k-chunks of 32
    int L = vlen[b];
    int k0 = kc * 32;
    if (k0 >= L) return;             // fully masked chunk: uniform exit
    int q0 = qc * 32;

    int tid = threadIdx.x;
    {
        int c4 = tid & 63, r0 = tid >> 6;
        const float4* gq = (const float4*)(Eq + ((size_t)b * NQ + q0) * HH);
        const float4* gk = (const float4*)(Ek + ((size_t)b * NK + k0) * HH);
#pragma unroll
        for (int r = 0; r < 32; r += 4) {
            *(float4*)&sQ[r + r0][c4 * 4] = gq[(size_t)(r + r0) * (HH / 4) + c4];
            *(float4*)&sK[r + r0][c4 * 4] = gk[(size_t)(r + r0) * (HH / 4) + c4];
        }
        sW[tid] = wv[tid];
    }
    __syncthreads();

    int ki = tid & 15, qi = tid >> 4;
    float a00 = 0.f, a01 = 0.f, a10 = 0.f, a11 = 0.f;
    const float4* qp0 = (const float4*)&sQ[qi][0];
    const float4* qp1 = (const float4*)&sQ[qi + 16][0];
    const float4* kp0 = (const float4*)&sK[ki][0];
    const float4* kp1 = (const float4*)&sK[ki + 16][0];
    const float4* wp  = (const float4*)sW;

#pragma unroll 4
    for (int h4 = 0; h4 < HH / 4; ++h4) {
        float4 w = wp[h4];
        float wxy = w.x + w.y, wzw = w.z + w.w;
        float4 A0 = qp0[h4], A1 = qp1[h4];
        float4 B0 = kp0[h4], B1 = kp1[h4];
#define QUAD(acc, Aq, Bk)                                                    \
        {                                                                    \
            float E1 = Aq.x * Bk.x, E2 = Aq.y * Bk.y;                        \
            float E3 = Aq.z * Bk.z, E4 = Aq.w * Bk.w;                        \
            float d1 = E1 + 1.f, d2 = E2 + 1.f;                              \
            float d3 = E3 + 1.f, d4 = E4 + 1.f;                              \
            float n12 = fmaf(w.x, E2, fmaf(w.y, E1, wxy));                   \
            float n34 = fmaf(w.z, E4, fmaf(w.w, E3, wzw));                   \
            float d12 = d1 * d2, d34 = d3 * d4;                              \
            float num = fmaf(n12, d34, n34 * d12);                           \
            acc = fmaf(num, __builtin_amdgcn_rcpf(d12 * d34), acc);          \
        }
        QUAD(a00, A0, B0);
        QUAD(a01, A0, B1);
        QUAD(a10, A1, B0);
        QUAD(a11, A1, B1);
#undef QUAD
    }

    int kA = k0 + ki, kB = kA + 16;
    float p00 = (kA < L) ? __expf(-2.f * a00) : 0.f;
    float p10 = (kA < L) ? __expf(-2.f * a10) : 0.f;
    float p01 = (kB < L) ? __expf(-2.f * a01) : 0.f;
    float p11 = (kB < L) ? __expf(-2.f * a11) : 0.f;

    float* s0 = P + ((size_t)b * NQ + q0 + qi) * NK;
    float* s1 = P + ((size_t)b * NQ + q0 + qi + 16) * NK;
    s0[kA] = p00; s0[kB] = p01;
    s1[kA] = p10; s1[kB] = p11;

    float r0s = p00 + p01, r1s = p10 + p11;
#pragma unroll
    for (int o = 1; o <= 8; o <<= 1) {
        r0s += __shfl_xor(r0s, o, 64);
        r1s += __shfl_xor(r1s, o, 64);
    }
    if (ki == 0) {
        Psum[((size_t)b * NQ + q0 + qi) * 32 + kc] = r0s;
        Psum[((size_t)b * NQ + q0 + qi + 16) * 32 + kc] = r1s;
    }
}

// ---------------- K3: PV GEMM + normalize ----------------
// 32q x 32d per block, 4x4 micro, 4-way k-split across waves. DEPTH-2
// register prefetch: two chunks in flight so ~512 compute cycles cover one
// L2 round-trip. One barrier per chunk. out = (P @ V) / rowsum.
__global__ __launch_bounds__(256) void pv_kernel(
    const float* __restrict__ P, const float* __restrict__ V,
    const float* __restrict__ Psum, const int* __restrict__ vlen,
    float* __restrict__ out)
{
    __shared__ __align__(16) float sPt[2][32][36];   // [k][q]
    __shared__ __align__(16) float sV[2][32][36];    // [k][d]
    __shared__ float sAll[3][64][17];
    __shared__ float sRowsum[32];

    int bid = blockIdx.x;
    int b = bid & 3;
    int rest = bid >> 2;
    int qt = rest >> 3, dt = rest & 7;
    int q0 = qt * 32, d0 = dt * 32;
    int L = vlen[b];
    int nc = (L + 31) >> 5;

    int tid = threadIdx.x;
    if (tid < 32) {
        float s = 0.f;
        const float* pp = Psum + ((size_t)b * NQ + q0 + tid) * 32;
        for (int c = 0; c < nc; ++c) s += pp[c];
        sRowsum[tid] = s;
    }

    int r = tid >> 3, c4 = tid & 7;
    int w = tid >> 6, sp = tid & 63;
    int qg = sp >> 3, dg = sp & 7;

    const float* Pb = P + ((size_t)b * NQ + q0 + r) * NK;
    const float* Vb = V + (size_t)b * NK * DD + d0;

    // depth-2 prefetch
    float4 pf0 = *(const float4*)(Pb + c4 * 4);
    float4 vf0 = *(const float4*)(Vb + (size_t)r * DD + c4 * 4);
    int c1i = (nc > 1) ? 32 : 0;
    float4 pf1 = *(const float4*)(Pb + c1i + c4 * 4);
    float4 vf1 = *(const float4*)(Vb + (size_t)(c1i + r) * DD + c4 * 4);

    float acc[4][4] = {};

    for (int c = 0; c < nc; ++c) {
        int cur = c & 1;
        if (cur == 0) {
            sPt[0][c4 * 4 + 0][r] = pf0.x;
            sPt[0][c4 * 4 + 1][r] = pf0.y;
            sPt[0][c4 * 4 + 2][r] = pf0.z;
            sPt[0][c4 * 4 + 3][r] = pf0.w;
            *(float4*)&sV[0][r][c4 * 4] = vf0;
            if (c + 2 < nc) {
                int kn = (c + 2) * 32;
                pf0 = *(const float4*)(Pb + kn + c4 * 4);
                vf0 = *(const float4*)(Vb + (size_t)(kn + r) * DD + c4 * 4);
            }
        } else {
            sPt[1][c4 * 4 + 0][r] = pf1.x;
            sPt[1][c4 * 4 + 1][r] = pf1.y;
            sPt[1][c4 * 4 + 2][r] = pf1.z;
            sPt[1][c4 * 4 + 3][r] = pf1.w;
            *(float4*)&sV[1][r][c4 * 4] = vf1;
            if (c + 2 < nc) {
                int kn = (c + 2) * 32;
                pf1 = *(const float4*)(Pb + kn + c4 * 4);
                vf1 = *(const float4*)(Vb + (size_t)(kn + r) * DD + c4 * 4);
            }
        }
        __syncthreads();
#pragma unroll
        for (int kk = 0; kk < 8; ++kk) {
            float4 A  = *(const float4*)&sPt[cur][w * 8 + kk][qg * 4];
            float4 Bv = *(const float4*)&sV[cur][w * 8 + kk][dg * 4];
            acc[0][0] = fmaf(A.x, Bv.x, acc[0][0]);
            acc[0][1] = fmaf(A.x, Bv.y, acc[0][1]);
            acc[0][2] = fmaf(A.x, Bv.z, acc[0][2]);
            acc[0][3] = fmaf(A.x, Bv.w, acc[0][3]);
            acc[1][0] = fmaf(A.y, Bv.x, acc[1][0]);
            acc[1][1] = fmaf(A.y, Bv.y, acc[1][1]);
            acc[1][2] = fmaf(A.y, Bv.z, acc[1][2]);
            acc[1][3] = fmaf(A.y, Bv.w, acc[1][3]);
            acc[2][0] = fmaf(A.z, Bv.x, acc[2][0]);
            acc[2][1] = fmaf(A.z, Bv.y, acc[2][1]);
            acc[2][2] = fmaf(A.z, Bv.z, acc[2][2]);
            acc[2][3] = fmaf(A.z, Bv.w, acc[2][3]);
            acc[3][0] = fmaf(A.w, Bv.x, acc[3][0]);
            acc[3][1] = fmaf(A.w, Bv.y, acc[3][1]);
            acc[3][2] = fmaf(A.w, Bv.z, acc[3][2]);
            acc[3][3] = fmaf(A.w, Bv.w, acc[3][3]);
        }
        // single barrier per chunk: barrier(c-1) separates compute(c-2)
        // from write(c) into the same buffer
    }

    if (w > 0) {
#pragma unroll
        for (int i = 0; i < 4; ++i)
#pragma unroll
            for (int j = 0; j < 4; ++j) sAll[w - 1][sp][i * 4 + j] = acc[i][j];
    }
    __syncthreads();
    if (w == 0) {
#pragma unroll
        for (int ww = 0; ww < 3; ++ww)
#pragma unroll
            for (int i = 0; i < 4; ++i)
#pragma unroll
                for (int j = 0; j < 4; ++j) acc[i][j] += sAll[ww][sp][i * 4 + j];
#pragma unroll
        for (int i = 0; i < 4; ++i) {
            float inv = 1.0f / sRowsum[qg * 4 + i];
            float4 o = { acc[i][0] * inv, acc[i][1] * inv,
                         acc[i][2] * inv, acc[i][3] * inv };
            *(float4*)&out[((size_t)b * NQ + q0 + qg * 4 + i) * DD + d0 + dg * 4] = o;
        }
    }
}

extern "C" void kernel_launch(void* const* d_in, const int* in_sizes, int n_in,
                              void* d_out, int out_size, void* d_ws, size_t ws_size,
                              hipStream_t stream) {
    const float* queries = (const float*)d_in[0];  // [B,NQ,D]
    const float* keys    = (const float*)d_in[1];  // [B,NK,D]
    const float* values  = (const float*)d_in[2];  // [B,NK,D]
    const int*   vlens   = (const int*)d_in[3];    // [B]
    const float* Wq      = (const float*)d_in[4];  // [D,H]
    const float* Wk      = (const float*)d_in[5];  // [D,H]
    const float* wv      = (const float*)d_in[6];  // [H]
    float* out = (float*)d_out;

    float* Eqb  = (float*)d_ws;                          // 1 MB
    float* Ekb  = Eqb + (size_t)BB * NQ * HH;            // 4 MB
    float* P    = Ekb + (size_t)BB * NK * HH;            // 4 MB
    float* Psum = P + (size_t)BB * NQ * NK;              // 128 KB [b][q][32]

    // 640 blocks: (32 q-tiles + 128 k-tiles) x 4 col-tiles
    proj_exp_kernel<<<dim3(((BB * NQ) / TMR + (BB * NK) / TMR) * 4), 256, 0,
                      stream>>>(queries, keys, Wq, Wk, vlens, Eqb, Ekb);

    scores_kernel<<<dim3(BB * (NQ / 32) * (NK / 32)), 256, 0, stream>>>(
        Eqb, Ekb, wv, vlens, P, Psum);

    pv_kernel<<<dim3(BB * (NQ / 32) * (DD / 32)), 256, 0, stream>>>(
        P, values, Psum, vlens, out);
}

// Round 9
// 57.209 us; speedup vs baseline: 5.9836x; 1.0326x over previous
//
#include <hip/hip_runtime.h>
#include <hip/hip_fp16.h>
#include <math.h>

#define BB 4
#define NQ 256
#define NK 1024
#define DD 256
#define HH 256

// ---------------- K1: Projection GEMM (fp32) + E=exp(2x) epilogue, fp16 out -
// E[m,h] = exp(2*clamp(sum_d A[m,d]*W[d,h], -5.5, 5.5)) stored as fp16.
// clamp +-5.5: e^11=59874 < fp16 max 65504; |tanh| error < 4e-5.
// tanh(z) = 1 - 2/(1+e^{2z}) applied implicitly downstream (sum_h w_h
// cancels in softmax). Fully-masked K-tiles exit early.
#define TMR 32
#define TNC 64
#define TKK 16
#define NT (DD / TKK)   // 16 k-steps

__global__ __launch_bounds__(256) void proj_exp_kernel(
    const float* __restrict__ Q, const float* __restrict__ K,
    const float* __restrict__ Wq, const float* __restrict__ Wk,
    const int* __restrict__ vlen,
    __half* __restrict__ Eq, __half* __restrict__ Ek)
{
    const int QROWT = (BB * NQ) / TMR;   // 32 q row-tiles
    int bx = blockIdx.x;
    int rt = bx >> 2, ct = bx & 3;
    const float* A; const float* W; __half* C; int bm;
    if (rt < QROWT) { A = Q; W = Wq; C = Eq; bm = rt * TMR; }
    else {
        int kt = rt - QROWT;             // 0..127
        int b = kt >> 5;
        int lr = (kt & 31) * TMR;        // batch-local row start
        if (lr >= vlen[b]) return;       // fully masked K-tile: skip
        A = K; W = Wk; C = Ek; bm = kt * TMR;
    }
    int bn = ct * TNC;

    __shared__ float As[2][TKK][TMR + 2];   // [k][m]
    __shared__ float Ws[2][TKK][TNC + 4];   // [k][n]

    int tid = threadIdx.x;
    int ar = (tid >> 2) & 31, ac4 = tid & 3;   // A stager (tid<128)
    int wkk = tid >> 4, wc4 = tid & 15;        // W stager (all)
    int ty = tid >> 4, tx = tid & 15;          // compute: 2 rows, 4 cols

    float4 aR = {0,0,0,0}, wR;
    if (tid < 128) aR = *(const float4*)&A[(size_t)(bm + ar) * DD + ac4 * 4];
    wR = *(const float4*)&W[(size_t)wkk * HH + bn + wc4 * 4];

    float acc[2][4] = {};

    for (int t = 0; t < NT; ++t) {
        int cur = t & 1;
        if (tid < 128) {
            As[cur][ac4 * 4 + 0][ar] = aR.x;
            As[cur][ac4 * 4 + 1][ar] = aR.y;
            As[cur][ac4 * 4 + 2][ar] = aR.z;
            As[cur][ac4 * 4 + 3][ar] = aR.w;
        }
        *(float4*)&Ws[cur][wkk][wc4 * 4] = wR;
        if (t + 1 < NT) {
            int k0 = (t + 1) * TKK;
            if (tid < 128)
                aR = *(const float4*)&A[(size_t)(bm + ar) * DD + k0 + ac4 * 4];
            wR = *(const float4*)&W[(size_t)(k0 + wkk) * HH + bn + wc4 * 4];
        }
        __syncthreads();
#pragma unroll
        for (int kk = 0; kk < TKK; ++kk) {
            float2 a2 = *(const float2*)&As[cur][kk][ty * 2];
            float4 w4 = *(const float4*)&Ws[cur][kk][tx * 4];
            acc[0][0] = fmaf(a2.x, w4.x, acc[0][0]);
            acc[0][1] = fmaf(a2.x, w4.y, acc[0][1]);
            acc[0][2] = fmaf(a2.x, w4.z, acc[0][2]);
            acc[0][3] = fmaf(a2.x, w4.w, acc[0][3]);
            acc[1][0] = fmaf(a2.y, w4.x, acc[1][0]);
            acc[1][1] = fmaf(a2.y, w4.y, acc[1][1]);
            acc[1][2] = fmaf(a2.y, w4.z, acc[1][2]);
            acc[1][3] = fmaf(a2.y, w4.w, acc[1][3]);
        }
        // dbuf: next iter writes the other buffer; barrier above suffices
    }

#pragma unroll
    for (int i = 0; i < 2; ++i) {
        int m = bm + ty * 2 + i;
        __half h[4];
#pragma unroll
        for (int j = 0; j < 4; ++j)
            h[j] = __float2half(__expf(2.f * fminf(fmaxf(acc[i][j], -5.5f), 5.5f)));
        *(ushort4*)&C[(size_t)m * HH + bn + tx * 4] = *(ushort4*)h;
    }
}

// ---------------- K2: scores -> P = exp(-2T) + per-chunk row sums -----------
// T(q,k) = sum_h w_h/(1+Eq_h*Ek_h); logit = -2T. fp16 E tiles -> 34 KB LDS
// -> 4 blocks/CU (2x the waves of the f32 version). Quad-batched rational:
// one v_rcp per 4 h-terms. Masked k -> P = 0. Deterministic Psum via shfl.
__global__ __launch_bounds__(256) void scores_kernel(
    const __half* __restrict__ Eq, const __half* __restrict__ Ek,
    const float* __restrict__ wv, const int* __restrict__ vlen,
    float* __restrict__ P, float* __restrict__ Psum)
{
    __shared__ __align__(16) __half sQ[32][HH + 8];   // stride 528 B: 4-bank rot
    __shared__ __align__(16) __half sK[32][HH + 8];
    __shared__ __align__(16) float sW[HH];

    int bid = blockIdx.x;
    int b = bid & 3;                 // batch-interleaved for balance
    int rest = bid >> 2;
    int qc = rest & 7;               // 8 q-chunks of 32
    int kc = rest >> 3;              // 32 k-chunks of 32
    int L = vlen[b];
    int k0 = kc * 32;
    if (k0 >= L) return;             // fully masked chunk: uniform exit
    int q0 = qc * 32;

    int tid = threadIdx.x;
    {
        int c8 = tid & 31;           // 16B chunk within a 512B row
        int r0 = tid >> 5;           // 0..7
        const __half* gq = Eq + ((size_t)b * NQ + q0) * HH;
        const __half* gk = Ek + ((size_t)b * NK + k0) * HH;
#pragma unroll
        for (int i = 0; i < 4; ++i) {
            int r = r0 + 8 * i;
            *(uint4*)&sQ[r][c8 * 8] = *(const uint4*)&gq[(size_t)r * HH + c8 * 8];
            *(uint4*)&sK[r][c8 * 8] = *(const uint4*)&gk[(size_t)r * HH + c8 * 8];
        }
        sW[tid] = wv[tid];
    }
    __syncthreads();

    int ki = tid & 15, qi = tid >> 4;
    float a00 = 0.f, a01 = 0.f, a10 = 0.f, a11 = 0.f;

#pragma unroll 4
    for (int h4 = 0; h4 < HH / 4; ++h4) {
        float4 w = *(const float4*)&sW[h4 * 4];
        float wxy = w.x + w.y, wzw = w.z + w.w;
        // unpack fp16 quads to f32
        float2 q0a = __half22float2(*(const __half2*)&sQ[qi][h4 * 4]);
        float2 q0b = __half22float2(*(const __half2*)&sQ[qi][h4 * 4 + 2]);
        float2 q1a = __half22float2(*(const __half2*)&sQ[qi + 16][h4 * 4]);
        float2 q1b = __half22float2(*(const __half2*)&sQ[qi + 16][h4 * 4 + 2]);
        float2 k0a = __half22float2(*(const __half2*)&sK[ki][h4 * 4]);
        float2 k0b = __half22float2(*(const __half2*)&sK[ki][h4 * 4 + 2]);
        float2 k1a = __half22float2(*(const __half2*)&sK[ki + 16][h4 * 4]);
        float2 k1b = __half22float2(*(const __half2*)&sK[ki + 16][h4 * 4 + 2]);
        float4 A0 = {q0a.x, q0a.y, q0b.x, q0b.y};
        float4 A1 = {q1a.x, q1a.y, q1b.x, q1b.y};
        float4 B0 = {k0a.x, k0a.y, k0b.x, k0b.y};
        float4 B1 = {k1a.x, k1a.y, k1b.x, k1b.y};
#define QUAD(acc, Aq, Bk)                                                    \
        {                                                                    \
            float E1 = Aq.x * Bk.x, E2 = Aq.y * Bk.y;                        \
            float E3 = Aq.z * Bk.z, E4 = Aq.w * Bk.w;                        \
            float d1 = E1 + 1.f, d2 = E2 + 1.f;                              \
            float d3 = E3 + 1.f, d4 = E4 + 1.f;                              \
            float n12 = fmaf(w.x, E2, fmaf(w.y, E1, wxy));                   \
            float n34 = fmaf(w.z, E4, fmaf(w.w, E3, wzw));                   \
            float d12 = d1 * d2, d34 = d3 * d4;                              \
            float num = fmaf(n12, d34, n34 * d12);                           \
            acc = fmaf(num, __builtin_amdgcn_rcpf(d12 * d34), acc);          \
        }
        QUAD(a00, A0, B0);
        QUAD(a01, A0, B1);
        QUAD(a10, A1, B0);
        QUAD(a11, A1, B1);
#undef QUAD
    }

    int kA = k0 + ki, kB = kA + 16;
    float p00 = (kA < L) ? __expf(-2.f * a00) : 0.f;
    float p10 = (kA < L) ? __expf(-2.f * a10) : 0.f;
    float p01 = (kB < L) ? __expf(-2.f * a01) : 0.f;
    float p11 = (kB < L) ? __expf(-2.f * a11) : 0.f;

    float* s0 = P + ((size_t)b * NQ + q0 + qi) * NK;
    float* s1 = P + ((size_t)b * NQ + q0 + qi + 16) * NK;
    s0[kA] = p00; s0[kB] = p01;
    s1[kA] = p10; s1[kB] = p11;

    float r0s = p00 + p01, r1s = p10 + p11;
#pragma unroll
    for (int o = 1; o <= 8; o <<= 1) {
        r0s += __shfl_xor(r0s, o, 64);
        r1s += __shfl_xor(r1s, o, 64);
    }
    if (ki == 0) {
        Psum[((size_t)b * NQ + q0 + qi) * 32 + kc] = r0s;
        Psum[((size_t)b * NQ + q0 + qi + 16) * 32 + kc] = r1s;
    }
}

// ---------------- K3: PV GEMM + normalize (unchanged, known-good) -----------
__global__ __launch_bounds__(256) void pv_kernel(
    const float* __restrict__ P, const float* __restrict__ V,
    const float* __restrict__ Psum, const int* __restrict__ vlen,
    float* __restrict__ out)
{
    __shared__ __align__(16) float sPt[2][32][36];   // [k][q]
    __shared__ __align__(16) float sV[2][32][36];    // [k][d]
    __shared__ float sAll[3][64][17];
    __shared__ float sRowsum[32];

    int bid = blockIdx.x;
    int b = bid & 3;
    int rest = bid >> 2;
    int qt = rest >> 3, dt = rest & 7;
    int q0 = qt * 32, d0 = dt * 32;
    int L = vlen[b];
    int nc = (L + 31) >> 5;

    int tid = threadIdx.x;
    if (tid < 32) {
        float s = 0.f;
        const float* pp = Psum + ((size_t)b * NQ + q0 + tid) * 32;
        for (int c = 0; c < nc; ++c) s += pp[c];
        sRowsum[tid] = s;
    }

    int r = tid >> 3, c4 = tid & 7;
    int w = tid >> 6, sp = tid & 63;
    int qg = sp >> 3, dg = sp & 7;

    const float* Pb = P + ((size_t)b * NQ + q0 + r) * NK;
    const float* Vb = V + (size_t)b * NK * DD + d0;

    float4 pf = *(const float4*)(Pb + c4 * 4);
    float4 vf = *(const float4*)(Vb + (size_t)r * DD + c4 * 4);

    float acc[4][4] = {};

    for (int c = 0; c < nc; ++c) {
        int cur = c & 1;
        sPt[cur][c4 * 4 + 0][r] = pf.x;
        sPt[cur][c4 * 4 + 1][r] = pf.y;
        sPt[cur][c4 * 4 + 2][r] = pf.z;
        sPt[cur][c4 * 4 + 3][r] = pf.w;
        *(float4*)&sV[cur][r][c4 * 4] = vf;
        if (c + 1 < nc) {
            int kn = (c + 1) * 32;
            pf = *(const float4*)(Pb + kn + c4 * 4);
            vf = *(const float4*)(Vb + (size_t)(kn + r) * DD + c4 * 4);
        }
        __syncthreads();
#pragma unroll
        for (int kk = 0; kk < 8; ++kk) {
            float4 A  = *(const float4*)&sPt[cur][w * 8 + kk][qg * 4];
            float4 Bv = *(const float4*)&sV[cur][w * 8 + kk][dg * 4];
            acc[0][0] = fmaf(A.x, Bv.x, acc[0][0]);
            acc[0][1] = fmaf(A.x, Bv.y, acc[0][1]);
            acc[0][2] = fmaf(A.x, Bv.z, acc[0][2]);
            acc[0][3] = fmaf(A.x, Bv.w, acc[0][3]);
            acc[1][0] = fmaf(A.y, Bv.x, acc[1][0]);
            acc[1][1] = fmaf(A.y, Bv.y, acc[1][1]);
            acc[1][2] = fmaf(A.y, Bv.z, acc[1][2]);
            acc[1][3] = fmaf(A.y, Bv.w, acc[1][3]);
            acc[2][0] = fmaf(A.z, Bv.x, acc[2][0]);
            acc[2][1] = fmaf(A.z, Bv.y, acc[2][1]);
            acc[2][2] = fmaf(A.z, Bv.z, acc[2][2]);
            acc[2][3] = fmaf(A.z, Bv.w, acc[2][3]);
            acc[3][0] = fmaf(A.w, Bv.x, acc[3][0]);
            acc[3][1] = fmaf(A.w, Bv.y, acc[3][1]);
            acc[3][2] = fmaf(A.w, Bv.z, acc[3][2]);
            acc[3][3] = fmaf(A.w, Bv.w, acc[3][3]);
        }
    }

    if (w > 0) {
#pragma unroll
        for (int i = 0; i < 4; ++i)
#pragma unroll
            for (int j = 0; j < 4; ++j) sAll[w - 1][sp][i * 4 + j] = acc[i][j];
    }
    __syncthreads();
    if (w == 0) {
#pragma unroll
        for (int ww = 0; ww < 3; ++ww)
#pragma unroll
            for (int i = 0; i < 4; ++i)
#pragma unroll
                for (int j = 0; j < 4; ++j) acc[i][j] += sAll[ww][sp][i * 4 + j];
#pragma unroll
        for (int i = 0; i < 4; ++i) {
            float inv = 1.0f / sRowsum[qg * 4 + i];
            float4 o = { acc[i][0] * inv, acc[i][1] * inv,
                         acc[i][2] * inv, acc[i][3] * inv };
            *(float4*)&out[((size_t)b * NQ + q0 + qg * 4 + i) * DD + d0 + dg * 4] = o;
        }
    }
}

extern "C" void kernel_launch(void* const* d_in, const int* in_sizes, int n_in,
                              void* d_out, int out_size, void* d_ws, size_t ws_size,
                              hipStream_t stream) {
    const float* queries = (const float*)d_in[0];  // [B,NQ,D]
    const float* keys    = (const float*)d_in[1];  // [B,NK,D]
    const float* values  = (const float*)d_in[2];  // [B,NK,D]
    const int*   vlens   = (const int*)d_in[3];    // [B]
    const float* Wq      = (const float*)d_in[4];  // [D,H]
    const float* Wk      = (const float*)d_in[5];  // [D,H]
    const float* wv      = (const float*)d_in[6];  // [H]
    float* out = (float*)d_out;

    __half* Eqh = (__half*)d_ws;                         // 512 KB
    __half* Ekh = Eqh + (size_t)BB * NQ * HH;            // 2 MB
    float*  P    = (float*)(Ekh + (size_t)BB * NK * HH); // 4 MB
    float*  Psum = P + (size_t)BB * NQ * NK;             // 128 KB [b][q][32]

    // 640 blocks: (32 q-tiles + 128 k-tiles) x 4 col-tiles
    proj_exp_kernel<<<dim3(((BB * NQ) / TMR + (BB * NK) / TMR) * 4), 256, 0,
                      stream>>>(queries, keys, Wq, Wk, vlens, Eqh, Ekh);

    scores_kernel<<<dim3(BB * (NQ / 32) * (NK / 32)), 256, 0, stream>>>(
        Eqh, Ekh, wv, vlens, P, Psum);

    pv_kernel<<<dim3(BB * (NQ / 32) * (DD / 32)), 256, 0, stream>>>(
        P, values, Psum, vlens, out);
}

// Round 10
// 54.934 us; speedup vs baseline: 6.2313x; 1.0414x over previous
//
#include <hip/hip_runtime.h>
#include <hip/hip_fp16.h>
#include <math.h>

#define BB 4
#define NQ 256
#define NK 1024
#define DD 256
#define HH 256

typedef __attribute__((ext_vector_type(8))) _Float16 f16x8;
typedef __attribute__((ext_vector_type(4))) _Float16 f16x4;
typedef __attribute__((ext_vector_type(4))) float f32x4;

// ---------------- K1: MFMA-f16 projection + E=exp(2x) epilogue --------------
// E[m,h] = exp(2*clamp(proj, -5.5, 5.5)) as fp16 (e^11 = 59874 < 65504).
// tanh(z) = 1 - 2/(1+e^{2z}) applied implicitly downstream.
// Grid: 80 m-tiles(64 rows) x 8 n-tiles(32 cols) = 640 blocks, 4 waves each.
// Per wave: 32m x 16n = 2 MFMA tiles. A-frags direct-from-global f32x4 + cvt;
// B-frags from one-time W^T fp16 LDS tile (stride 260 halves: 8B-aligned b64,
// conflict-free). No barriers in the k-loop. k-permutation consistency between
// A and B frags makes the result independent of the HW k-ordering.
__global__ __launch_bounds__(256) void proj_mfma_kernel(
    const float* __restrict__ Q, const float* __restrict__ K,
    const float* __restrict__ Wq, const float* __restrict__ Wk,
    const int* __restrict__ vlen,
    __half* __restrict__ Eq, __half* __restrict__ Ek)
{
    int bx = blockIdx.x;
    int mt = bx >> 3, nt = bx & 7;
    const float *A, *W; __half* C; int bm;
    if (mt < 16) { A = Q; W = Wq; C = Eq; bm = mt * 64; }
    else {
        int kt = mt - 16;                 // 0..63
        int b = kt >> 4;
        int lr = (kt & 15) * 64;          // batch-local row start
        if (lr >= vlen[b]) return;        // fully masked K-tile: skip
        A = K; W = Wk; C = Ek; bm = kt * 64;
    }
    int bn = nt * 32;

    __shared__ __half Wt[32][260];        // [n][d] transposed W tile, fp16

    int tid = threadIdx.x;
    {   // one-time W^T stage: coalesced f32 reads, packed __half2 writes
        int dp = tid >> 3, cg = tid & 7;  // 32 d-pairs x 8 col-groups
#pragma unroll
        for (int pp = 0; pp < 4; ++pp) {
            int d0r = (dp + pp * 32) * 2;
            float4 r0 = *(const float4*)&W[(size_t)d0r * HH + bn + cg * 4];
            float4 r1 = *(const float4*)&W[(size_t)(d0r + 1) * HH + bn + cg * 4];
            int n = cg * 4;
            *(__half2*)&Wt[n + 0][d0r] = __floats2half2_rn(r0.x, r1.x);
            *(__half2*)&Wt[n + 1][d0r] = __floats2half2_rn(r0.y, r1.y);
            *(__half2*)&Wt[n + 2][d0r] = __floats2half2_rn(r0.z, r1.z);
            *(__half2*)&Wt[n + 3][d0r] = __floats2half2_rn(r0.w, r1.w);
        }
    }
    __syncthreads();

    int lane = tid & 63, w = tid >> 6;
    int wm = w & 1, wn = w >> 1;          // wave covers 32m x 16n
    int lm = lane & 15, lk = (lane >> 4) * 4;

    const float* arow0 = A + (size_t)(bm + wm * 32 + lm) * DD;   // mi=0
    const float* arow1 = arow0 + (size_t)16 * DD;                // mi=1
    const __half* brow = &Wt[wn * 16 + lm][0];

    f32x4 acc0 = {0.f, 0.f, 0.f, 0.f};
    f32x4 acc1 = {0.f, 0.f, 0.f, 0.f};

    // depth-1 prefetch registers
    float4 a00 = *(const float4*)(arow0 + lk);
    float4 a01 = *(const float4*)(arow0 + 16 + lk);
    float4 a10 = *(const float4*)(arow1 + lk);
    float4 a11 = *(const float4*)(arow1 + 16 + lk);
    f16x4 b0 = *(const f16x4*)&brow[lk];
    f16x4 b1 = *(const f16x4*)&brow[16 + lk];

#pragma unroll
    for (int s = 0; s < 8; ++s) {
        float4 c00 = a00, c01 = a01, c10 = a10, c11 = a11;
        f16x4 cb0 = b0, cb1 = b1;
        if (s < 7) {
            int d = (s + 1) * 32;
            a00 = *(const float4*)(arow0 + d + lk);
            a01 = *(const float4*)(arow0 + d + 16 + lk);
            a10 = *(const float4*)(arow1 + d + lk);
            a11 = *(const float4*)(arow1 + d + 16 + lk);
            b0 = *(const f16x4*)&brow[d + lk];
            b1 = *(const f16x4*)&brow[d + 16 + lk];
        }
        f16x8 af0, af1, bf;
        af0[0] = (_Float16)c00.x; af0[1] = (_Float16)c00.y;
        af0[2] = (_Float16)c00.z; af0[3] = (_Float16)c00.w;
        af0[4] = (_Float16)c01.x; af0[5] = (_Float16)c01.y;
        af0[6] = (_Float16)c01.z; af0[7] = (_Float16)c01.w;
        af1[0] = (_Float16)c10.x; af1[1] = (_Float16)c10.y;
        af1[2] = (_Float16)c10.z; af1[3] = (_Float16)c10.w;
        af1[4] = (_Float16)c11.x; af1[5] = (_Float16)c11.y;
        af1[6] = (_Float16)c11.z; af1[7] = (_Float16)c11.w;
        bf[0] = cb0[0]; bf[1] = cb0[1]; bf[2] = cb0[2]; bf[3] = cb0[3];
        bf[4] = cb1[0]; bf[5] = cb1[1]; bf[6] = cb1[2]; bf[7] = cb1[3];
        acc0 = __builtin_amdgcn_mfma_f32_16x16x32_f16(af0, bf, acc0, 0, 0, 0);
        acc1 = __builtin_amdgcn_mfma_f32_16x16x32_f16(af1, bf, acc1, 0, 0, 0);
    }

    // D layout (m89, dtype-independent): n = lane&15, m = (lane>>4)*4 + reg
    int mB0 = bm + wm * 32 + (lane >> 4) * 4;
    int mB1 = mB0 + 16;
    int n = bn + wn * 16 + lm;
#pragma unroll
    for (int r = 0; r < 4; ++r) {
        float e0 = __expf(2.f * fminf(fmaxf(acc0[r], -5.5f), 5.5f));
        float e1 = __expf(2.f * fminf(fmaxf(acc1[r], -5.5f), 5.5f));
        C[(size_t)(mB0 + r) * HH + n] = __float2half(e0);
        C[(size_t)(mB1 + r) * HH + n] = __float2half(e1);
    }
}

// ---------------- K2: scores -> P = exp(-2T) + per-chunk row sums -----------
// (byte-identical to R9, known-good)
__global__ __launch_bounds__(256) void scores_kernel(
    const __half* __restrict__ Eq, const __half* __restrict__ Ek,
    const float* __restrict__ wv, const int* __restrict__ vlen,
    float* __restrict__ P, float* __restrict__ Psum)
{
    __shared__ __align__(16) __half sQ[32][HH + 8];
    __shared__ __align__(16) __half sK[32][HH + 8];
    __shared__ __align__(16) float sW[HH];

    int bid = blockIdx.x;
    int b = bid & 3;
    int rest = bid >> 2;
    int qc = rest & 7;
    int kc = rest >> 3;
    int L = vlen[b];
    int k0 = kc * 32;
    if (k0 >= L) return;
    int q0 = qc * 32;

    int tid = threadIdx.x;
    {
        int c8 = tid & 31;
        int r0 = tid >> 5;
        const __half* gq = Eq + ((size_t)b * NQ + q0) * HH;
        const __half* gk = Ek + ((size_t)b * NK + k0) * HH;
#pragma unroll
        for (int i = 0; i < 4; ++i) {
            int r = r0 + 8 * i;
            *(uint4*)&sQ[r][c8 * 8] = *(const uint4*)&gq[(size_t)r * HH + c8 * 8];
            *(uint4*)&sK[r][c8 * 8] = *(const uint4*)&gk[(size_t)r * HH + c8 * 8];
        }
        sW[tid] = wv[tid];
    }
    __syncthreads();

    int ki = tid & 15, qi = tid >> 4;
    float a00 = 0.f, a01 = 0.f, a10 = 0.f, a11 = 0.f;

#pragma unroll 4
    for (int h4 = 0; h4 < HH / 4; ++h4) {
        float4 w = *(const float4*)&sW[h4 * 4];
        float wxy = w.x + w.y, wzw = w.z + w.w;
        float2 q0a = __half22float2(*(const __half2*)&sQ[qi][h4 * 4]);
        float2 q0b = __half22float2(*(const __half2*)&sQ[qi][h4 * 4 + 2]);
        float2 q1a = __half22float2(*(const __half2*)&sQ[qi + 16][h4 * 4]);
        float2 q1b = __half22float2(*(const __half2*)&sQ[qi + 16][h4 * 4 + 2]);
        float2 k0a = __half22float2(*(const __half2*)&sK[ki][h4 * 4]);
        float2 k0b = __half22float2(*(const __half2*)&sK[ki][h4 * 4 + 2]);
        float2 k1a = __half22float2(*(const __half2*)&sK[ki + 16][h4 * 4]);
        float2 k1b = __half22float2(*(const __half2*)&sK[ki + 16][h4 * 4 + 2]);
        float4 A0 = {q0a.x, q0a.y, q0b.x, q0b.y};
        float4 A1 = {q1a.x, q1a.y, q1b.x, q1b.y};
        float4 B0 = {k0a.x, k0a.y, k0b.x, k0b.y};
        float4 B1 = {k1a.x, k1a.y, k1b.x, k1b.y};
#define QUAD(acc, Aq, Bk)                                                    \
        {                                                                    \
            float E1 = Aq.x * Bk.x, E2 = Aq.y * Bk.y;                        \
            float E3 = Aq.z * Bk.z, E4 = Aq.w * Bk.w;                        \
            float d1 = E1 + 1.f, d2 = E2 + 1.f;                              \
            float d3 = E3 + 1.f, d4 = E4 + 1.f;                              \
            float n12 = fmaf(w.x, E2, fmaf(w.y, E1, wxy));                   \
            float n34 = fmaf(w.z, E4, fmaf(w.w, E3, wzw));                   \
            float d12 = d1 * d2, d34 = d3 * d4;                              \
            float num = fmaf(n12, d34, n34 * d12);                           \
            acc = fmaf(num, __builtin_amdgcn_rcpf(d12 * d34), acc);          \
        }
        QUAD(a00, A0, B0);
        QUAD(a01, A0, B1);
        QUAD(a10, A1, B0);
        QUAD(a11, A1, B1);
#undef QUAD
    }

    int kA = k0 + ki, kB = kA + 16;
    float p00 = (kA < L) ? __expf(-2.f * a00) : 0.f;
    float p10 = (kA < L) ? __expf(-2.f * a10) : 0.f;
    float p01 = (kB < L) ? __expf(-2.f * a01) : 0.f;
    float p11 = (kB < L) ? __expf(-2.f * a11) : 0.f;

    float* s0 = P + ((size_t)b * NQ + q0 + qi) * NK;
    float* s1 = P + ((size_t)b * NQ + q0 + qi + 16) * NK;
    s0[kA] = p00; s0[kB] = p01;
    s1[kA] = p10; s1[kB] = p11;

    float r0s = p00 + p01, r1s = p10 + p11;
#pragma unroll
    for (int o = 1; o <= 8; o <<= 1) {
        r0s += __shfl_xor(r0s, o, 64);
        r1s += __shfl_xor(r1s, o, 64);
    }
    if (ki == 0) {
        Psum[((size_t)b * NQ + q0 + qi) * 32 + kc] = r0s;
        Psum[((size_t)b * NQ + q0 + qi + 16) * 32 + kc] = r1s;
    }
}

// ---------------- K3: PV GEMM + normalize (unchanged, known-good) -----------
__global__ __launch_bounds__(256) void pv_kernel(
    const float* __restrict__ P, const float* __restrict__ V,
    const float* __restrict__ Psum, const int* __restrict__ vlen,
    float* __restrict__ out)
{
    __shared__ __align__(16) float sPt[2][32][36];
    __shared__ __align__(16) float sV[2][32][36];
    __shared__ float sAll[3][64][17];
    __shared__ float sRowsum[32];

    int bid = blockIdx.x;
    int b = bid & 3;
    int rest = bid >> 2;
    int qt = rest >> 3, dt = rest & 7;
    int q0 = qt * 32, d0 = dt * 32;
    int L = vlen[b];
    int nc = (L + 31) >> 5;

    int tid = threadIdx.x;
    if (tid < 32) {
        float s = 0.f;
        const float* pp = Psum + ((size_t)b * NQ + q0 + tid) * 32;
        for (int c = 0; c < nc; ++c) s += pp[c];
        sRowsum[tid] = s;
    }

    int r = tid >> 3, c4 = tid & 7;
    int w = tid >> 6, sp = tid & 63;
    int qg = sp >> 3, dg = sp & 7;

    const float* Pb = P + ((size_t)b * NQ + q0 + r) * NK;
    const float* Vb = V + (size_t)b * NK * DD + d0;

    float4 pf = *(const float4*)(Pb + c4 * 4);
    float4 vf = *(const float4*)(Vb + (size_t)r * DD + c4 * 4);

    float acc[4][4] = {};

    for (int c = 0; c < nc; ++c) {
        int cur = c & 1;
        sPt[cur][c4 * 4 + 0][r] = pf.x;
        sPt[cur][c4 * 4 + 1][r] = pf.y;
        sPt[cur][c4 * 4 + 2][r] = pf.z;
        sPt[cur][c4 * 4 + 3][r] = pf.w;
        *(float4*)&sV[cur][r][c4 * 4] = vf;
        if (c + 1 < nc) {
            int kn = (c + 1) * 32;
            pf = *(const float4*)(Pb + kn + c4 * 4);
            vf = *(const float4*)(Vb + (size_t)(kn + r) * DD + c4 * 4);
        }
        __syncthreads();
#pragma unroll
        for (int kk = 0; kk < 8; ++kk) {
            float4 A  = *(const float4*)&sPt[cur][w * 8 + kk][qg * 4];
            float4 Bv = *(const float4*)&sV[cur][w * 8 + kk][dg * 4];
            acc[0][0] = fmaf(A.x, Bv.x, acc[0][0]);
            acc[0][1] = fmaf(A.x, Bv.y, acc[0][1]);
            acc[0][2] = fmaf(A.x, Bv.z, acc[0][2]);
            acc[0][3] = fmaf(A.x, Bv.w, acc[0][3]);
            acc[1][0] = fmaf(A.y, Bv.x, acc[1][0]);
            acc[1][1] = fmaf(A.y, Bv.y, acc[1][1]);
            acc[1][2] = fmaf(A.y, Bv.z, acc[1][2]);
            acc[1][3] = fmaf(A.y, Bv.w, acc[1][3]);
            acc[2][0] = fmaf(A.z, Bv.x, acc[2][0]);
            acc[2][1] = fmaf(A.z, Bv.y, acc[2][1]);
            acc[2][2] = fmaf(A.z, Bv.z, acc[2][2]);
            acc[2][3] = fmaf(A.z, Bv.w, acc[2][3]);
            acc[3][0] = fmaf(A.w, Bv.x, acc[3][0]);
            acc[3][1] = fmaf(A.w, Bv.y, acc[3][1]);
            acc[3][2] = fmaf(A.w, Bv.z, acc[3][2]);
            acc[3][3] = fmaf(A.w, Bv.w, acc[3][3]);
        }
    }

    if (w > 0) {
#pragma unroll
        for (int i = 0; i < 4; ++i)
#pragma unroll
            for (int j = 0; j < 4; ++j) sAll[w - 1][sp][i * 4 + j] = acc[i][j];
    }
    __syncthreads();
    if (w == 0) {
#pragma unroll
        for (int ww = 0; ww < 3; ++ww)
#pragma unroll
            for (int i = 0; i < 4; ++i)
#pragma unroll
                for (int j = 0; j < 4; ++j) acc[i][j] += sAll[ww][sp][i * 4 + j];
#pragma unroll
        for (int i = 0; i < 4; ++i) {
            float inv = 1.0f / sRowsum[qg * 4 + i];
            float4 o = { acc[i][0] * inv, acc[i][1] * inv,
                         acc[i][2] * inv, acc[i][3] * inv };
            *(float4*)&out[((size_t)b * NQ + q0 + qg * 4 + i) * DD + d0 + dg * 4] = o;
        }
    }
}

extern "C" void kernel_launch(void* const* d_in, const int* in_sizes, int n_in,
                              void* d_out, int out_size, void* d_ws, size_t ws_size,
                              hipStream_t stream) {
    const float* queries = (const float*)d_in[0];  // [B,NQ,D]
    const float* keys    = (const float*)d_in[1];  // [B,NK,D]
    const float* values  = (const float*)d_in[2];  // [B,NK,D]
    const int*   vlens   = (const int*)d_in[3];    // [B]
    const float* Wq      = (const float*)d_in[4];  // [D,H]
    const float* Wk      = (const float*)d_in[5];  // [D,H]
    const float* wv      = (const float*)d_in[6];  // [H]
    float* out = (float*)d_out;

    __half* Eqh = (__half*)d_ws;                         // 512 KB
    __half* Ekh = Eqh + (size_t)BB * NQ * HH;            // 2 MB
    float*  P    = (float*)(Ekh + (size_t)BB * NK * HH); // 4 MB
    float*  Psum = P + (size_t)BB * NQ * NK;             // 128 KB

    // 640 blocks: 80 m-tiles(64) x 8 n-tiles(32)
    proj_mfma_kernel<<<dim3(640), 256, 0, stream>>>(
        queries, keys, Wq, Wk, vlens, Eqh, Ekh);

    scores_kernel<<<dim3(BB * (NQ / 32) * (NK / 32)), 256, 0, stream>>>(
        Eqh, Ekh, wv, vlens, P, Psum);

    pv_kernel<<<dim3(BB * (NQ / 32) * (DD / 32)), 256, 0, stream>>>(
        P, values, Psum, vlens, out);
}